// Round 16
// baseline (242.338 us; speedup 1.0000x reference)
//
#include <hip/hip_runtime.h>

// Problem constants (fixed by the reference)
#define BB 2
#define LL 2048
#define SS 2048
#define HH 16
#define EE 64
#define HE (HH*EE)          // fp32 elements per token row: 1024
#define TS 64               // s-cols per tile
#define SCALEF 0.125f       // 1/sqrt(64)
#define NEGBIG (-1e30f)     // -inf stand-in; exp underflows to exact 0

typedef __bf16 bf8 __attribute__((ext_vector_type(8)));
typedef float f4v __attribute__((ext_vector_type(4)));
typedef unsigned int u32;
typedef unsigned short u16;

// d_out layout (fp32 elements): V | A | entropy, concatenated in return order
#define V_ELEMS  ((size_t)BB*LL*HH*EE)              // 4,194,304
#define A_BASE   (V_ELEMS)
#define ENT_BASE (A_BASE + (size_t)BB*HH*LL*SS)     // + 134,217,728

__device__ __forceinline__ u16 bfb(float f) {  // fp32 -> bf16 RNE
    u32 u = __builtin_bit_cast(u32, f);
    return (u16)((u + 0x7fffu + ((u >> 16) & 1u)) >> 16);
}
// XOR swizzle on byte-addr bits 4-6 (LDS bank spread for 128B-row tiles)
__device__ __forceinline__ int swz8(int r) { return (((r) & 7) ^ (((r) >> 3) & 7)) << 4; }

__device__ __forceinline__ f4v mfma16(bf8 a, bf8 b, f4v c) {
    return __builtin_amdgcn_mfma_f32_16x16x32_bf16(a, b, c, 0, 0, 0);
}
// Masks may arrive as 1-byte bool or 4-byte int32 — runtime-detected.
__device__ __forceinline__ int maskv(const void* p, int i, int isB) {
    return isB ? (int)((const unsigned char*)p)[i] : ((const int*)p)[i];
}
// LDS-only barrier: waits ds ops, does NOT drain vmcnt — global loads/stores
// stay in flight across it (T14).
__device__ __forceinline__ void barrier_lds() {
    asm volatile("s_waitcnt lgkmcnt(0)" ::: "memory");
    __builtin_amdgcn_s_barrier();
    asm volatile("" ::: "memory");
}
__device__ __forceinline__ uint4 pack8(float4 f0, float4 f1) {  // 8 fp32 -> 8 bf16
    uint4 wv;
    wv.x = bfb(f0.x) | ((u32)bfb(f0.y) << 16);
    wv.y = bfb(f0.z) | ((u32)bfb(f0.w) << 16);
    wv.z = bfb(f1.x) | ((u32)bfb(f1.y) << 16);
    wv.w = bfb(f1.z) | ((u32)bfb(f1.w) << 16);
    return wv;
}

// Stage a 128x64 fp32 tile (row stride HE) into LDS as bf16 [128][64] swizzled. 512 thr.
__device__ __forceinline__ void stage128x64(const float* __restrict__ src,
                                            char* lds, int tid) {
    const int r = tid >> 2, seg = tid & 3;
    const float* rp = src + (size_t)r * HE + seg * 16;
    float4 f0 = *(const float4*)(rp + 0);
    float4 f1 = *(const float4*)(rp + 4);
    float4 f2 = *(const float4*)(rp + 8);
    float4 f3 = *(const float4*)(rp + 12);
    const int base = r * 128 + seg * 32;
    *(uint4*)(void*)(lds + ((base +  0) ^ swz8(r))) = pack8(f0, f1);
    *(uint4*)(void*)(lds + ((base + 16) ^ swz8(r))) = pack8(f2, f3);
}

// One block = (b, h, ONE 128-row band); 512 blocks x 512 thr -> 2 blocks/CU.
// R15 structure + (1) all zero-fills (masked rows + causal tails) issued
// BEFORE pass 1 so ~400MB of sequential stores drain under pass-1 compute,
// and (2) PAIRED-TILE A stores: buffer one tile's p in registers and write
// two tiles back-to-back -> per row 512B contiguous in 8 consecutive store
// instructions (DRAM open-page hits double).
__global__ __launch_bounds__(512, 4) void k_fused(
    const float* __restrict__ Qg, const float* __restrict__ Kg, const float* __restrict__ Vg,
    const void* __restrict__ mk, const void* __restrict__ mq,
    float* __restrict__ outF)
{
    __shared__ __align__(16) char ldsP[16384];      // Q stage / 8 wave-private 2KB P regions
    __shared__ __align__(16) char ldsK[2][8192];    // K dbuf [64 s][64 e] bf16
    __shared__ __align__(16) char ldsVT[2][8192];   // V^T dbuf [64 e][64 s] bf16
    __shared__ float ldsKM[SS];                     // k-mask bias row (8KB)
    __shared__ int sFlag;

    // Decode: XCD-major; band heavy-first (band 15 blocks dispatched first).
    const int blk = blockIdx.x;
    const int xcd = blk & 7, idx = blk >> 3;        // idx 0..63
    const int bh  = xcd * 4 + (idx & 3);            // 0..31
    const int band = 15 - (idx >> 2);               // 15..0, heavy first
    const int b = bh >> 4, h = bh & 15;
    const int tid = threadIdx.x;
    const int w = tid >> 6, lane = tid & 63, g = lane >> 4, le = lane & 15;

    int isB;   // mask element-width detection (1B bool vs 4B int32)
    {
        const unsigned char* c = (const unsigned char*)mk;
        unsigned acc = 0;
        #pragma unroll
        for (int j = 0; j < 8; ++j) {
            const int off = tid + j * 512;
            if (off & 3) acc |= c[off];
        }
        if (tid == 0) sFlag = 0;
        __syncthreads();
        if (acc) atomicOr(&sFlag, 1);
        __syncthreads();
        isB = sFlag;
    }
    for (int i = tid; i < SS; i += 512)
        ldsKM[i] = maskv(mk, b * SS + i, isB) ? NEGBIG : 0.f;

    const float* Qb = Qg + (size_t)b * LL * HE + h * EE;
    const float* Kb = Kg + (size_t)b * SS * HE + h * EE;
    const float* Vb = Vg + (size_t)b * SS * HE + h * EE;

    const int l0 = band * 128;
    const int lbase = l0 + w * 16 + g * 4;   // this lane's 4 C-layout rows
    const int whi = l0 + w * 16 + 15;        // wave's highest row
    const int ta  = whi >> 6;                // wave's last causal 64-col tile
    const int ntile = 2 * (band + 1);        // block-level causal tiles

    // q-masked flags for this lane's rows (depends only on mq -> known now)
    bool qm[4];
    #pragma unroll
    for (int r = 0; r < 4; ++r)
        qm[r] = maskv(mq, b * LL + lbase + r, isB) != 0;

    float* const Arow0 = outF + A_BASE + ((size_t)bh * LL + l0) * SS;

    // ---- EARLY zero-fills: issue ~400MB of sequential stores now so they
    //      drain under pass-1 compute (which has no stores). ----
    {   // q-masked rows: entire A row exactly 0 (1KB per instruction)
        const f4v zz = {0.f, 0.f, 0.f, 0.f};
        for (int k = 0; k < 16; ++k) {
            const int row = w * 16 + k;
            if (maskv(mq, b * LL + l0 + row, isB)) {
                float* dst = Arow0 + (size_t)row * SS + lane * 4;
                #pragma unroll
                for (int j = 0; j < 8; ++j)
                    *(f4v*)(void*)(dst + j * 256) = zz;
            }
        }
    }
    {   // causal zero-tail for NON-masked rows
        const int rr = lane >> 2, cc = lane & 3;
        const int row = w * 16 + rr;
        if (!maskv(mq, b * LL + l0 + row, isB)) {
            float* dst0 = Arow0 + (size_t)row * SS;
            const f4v zz = {0.f, 0.f, 0.f, 0.f};
            for (int c = (ta + 1) * TS + cc * 4; c < SS; c += 16)
                *(f4v*)(void*)(dst0 + c) = zz;
        }
    }

    // ---- stage Q tile [128][64] -> ldsP, grab fragments ----
    stage128x64(Qb + (size_t)l0 * HE, ldsP, tid);
    __syncthreads();
    const int qr = w * 16 + le;
    bf8 qf0 = *(const bf8*)(void*)(ldsP + ((qr * 128 +  0 + g * 16) ^ swz8(qr)));
    bf8 qf1 = *(const bf8*)(void*)(ldsP + ((qr * 128 + 64 + g * 16) ^ swz8(qr)));
    barrier_lds();   // ldsP free for P after this

    // per-thread staging geometry
    const int kr = tid >> 3, ksg = tid & 7;         // K: 64 rows x 8 segs of 8
    const float* kbase = Kb + (size_t)kr * HE + ksg * 8;
    const int koff = (kr * 128 + ksg * 16) ^ swz8(kr);
    const int vrp = tid >> 4, vei = tid & 15;       // V^T: 32 row-pairs x 16 e-quads
    const float* vbase = Vb + (size_t)(2 * vrp) * HE + vei * 4;

    // ================= PASS 1: per-row M, D, T (1 barrier/tile) =================
    float M[4], D[4], T[4];
    #pragma unroll
    for (int r = 0; r < 4; ++r) { M[r] = NEGBIG; D[r] = 0.f; T[r] = 0.f; }

    float4 ka = *(const float4*)(kbase);
    float4 kb2 = *(const float4*)(kbase + 4);
    *(uint4*)(void*)(&ldsK[0][0] + koff) = pack8(ka, kb2);
    if (ntile > 1) {
        const float* kp = kbase + (size_t)TS * HE;
        ka = *(const float4*)(kp); kb2 = *(const float4*)(kp + 4);
    }
    barrier_lds();
    int cur = 0;

    for (int st = 0; st < ntile; ++st) {
        const int s0 = st * TS;
        if (st + 1 < ntile) {   // stage next tile from regs, issue st+2 loads
            *(uint4*)(void*)(&ldsK[cur ^ 1][0] + koff) = pack8(ka, kb2);
            if (st + 2 < ntile) {
                const float* kp = kbase + (size_t)(st + 2) * TS * HE;
                ka = *(const float4*)(kp); kb2 = *(const float4*)(kp + 4);
            }
        }
        if (s0 <= whi) {   // causal skip
            f4v acc[4];
            float tm[4] = {NEGBIG, NEGBIG, NEGBIG, NEGBIG};
            #pragma unroll
            for (int cb = 0; cb < 4; ++cb) {
                const int sr = cb * 16 + le;
                bf8 k0 = *(const bf8*)(void*)(&ldsK[cur][0] + ((sr * 128 +  0 + g * 16) ^ swz8(sr)));
                bf8 k1 = *(const bf8*)(void*)(&ldsK[cur][0] + ((sr * 128 + 64 + g * 16) ^ swz8(sr)));
                f4v a = {0.f, 0.f, 0.f, 0.f};
                a = mfma16(qf0, k0, a);
                a = mfma16(qf1, k1, a);
                const float km = ldsKM[s0 + cb * 16 + le];
                const int s = s0 + cb * 16 + le;
                #pragma unroll
                for (int r = 0; r < 4; ++r) {
                    float z = a[r] * SCALEF + km;       // scale*(score + m_k)
                    if (s > lbase + r) z = NEGBIG;      // causal (pos == arange)
                    acc[cb][r] = z;
                    tm[r] = fmaxf(tm[r], z);
                }
            }
            // tile-level rescale: one shared max per row-tile, 1 exp per element
            #pragma unroll
            for (int r = 0; r < 4; ++r) {
                #pragma unroll
                for (int msk = 1; msk < 16; msk <<= 1)
                    tm[r] = fmaxf(tm[r], __shfl_xor(tm[r], msk));
                const float mn  = fmaxf(M[r], tm[r]);
                const float fre = __expf(M[r] - mn);    // 0 when jumping off -1e30
                float ed = 0.f, et = 0.f;
                #pragma unroll
                for (int cb = 0; cb < 4; ++cb) {
                    const float z = acc[cb][r];
                    const float e = __expf(z - mn);
                    ed += e; et += e * z;
                }
                D[r] = D[r] * fre + ed;
                T[r] = T[r] * fre + et;
                M[r] = mn;
            }
        }
        barrier_lds();
        cur ^= 1;
    }

    // butterfly-merge over the 16-lane group; C = logsumexp, entropy out
    float C[4];
    #pragma unroll
    for (int r = 0; r < 4; ++r) {
        #pragma unroll
        for (int msk = 1; msk < 16; msk <<= 1) {
            const float Mo = __shfl_xor(M[r], msk);
            const float Do = __shfl_xor(D[r], msk);
            const float To = __shfl_xor(T[r], msk);
            const float mn = fmaxf(M[r], Mo);
            const float fa = __expf(M[r] - mn);
            const float fb = __expf(Mo  - mn);
            D[r] = D[r] * fa + Do * fb;
            T[r] = T[r] * fa + To * fb;
            M[r] = mn;
        }
        const int l = lbase + r;
        const bool valid = (M[r] > -1e29f) && !qm[r];
        C[r] = valid ? (M[r] + __logf(D[r])) : 1e30f;     // p = exp(z - C); dead rows -> 0
        const float ent = valid ? (C[r] - T[r] / D[r]) : 0.f;
        if (le == 0) outF[ENT_BASE + (size_t)bh * LL + l] = ent;
    }

    // ================= PASS 2: A (paired-tile stores) + O = A·V =================
    f4v O[4];
    #pragma unroll
    for (int eb = 0; eb < 4; ++eb) O[eb] = (f4v){0.f, 0.f, 0.f, 0.f};

    ka  = *(const float4*)(kbase);
    kb2 = *(const float4*)(kbase + 4);
    float4 va  = *(const float4*)(vbase);
    float4 vb2 = *(const float4*)(vbase + HE);
    *(uint4*)(void*)(&ldsK[0][0] + koff) = pack8(ka, kb2);
    {
        const float* pa_ = &va.x; const float* pb_ = &vb2.x;
        #pragma unroll
        for (int i = 0; i < 4; ++i) {
            const int e = vei * 4 + i;
            const u32 pk = (u32)bfb(pa_[i]) | ((u32)bfb(pb_[i]) << 16);
            *(u32*)(void*)(&ldsVT[0][0] + ((e * 128 + vrp * 4) ^ swz8(e))) = pk;
        }
    }
    if (ntile > 1) {
        const float* kp = kbase + (size_t)TS * HE;
        const float* vp = vbase + (size_t)TS * HE;
        ka = *(const float4*)(kp); kb2 = *(const float4*)(kp + 4);
        va = *(const float4*)(vp); vb2 = *(const float4*)(vp + HE);
    }
    barrier_lds();
    cur = 0;
    char* const myP = ldsP + w * 2048;

    float pend[4][4];        // buffered p of the previous unstored tile [cb][r]
    int pbase = 0;
    bool havePend = false;

    for (int st = 0; st < ntile; ++st) {
        const int s0 = st * TS;
        if (st + 1 < ntile) {   // stage next tiles from regs, prefetch st+2
            *(uint4*)(void*)(&ldsK[cur ^ 1][0] + koff) = pack8(ka, kb2);
            {
                const float* pa_ = &va.x; const float* pb_ = &vb2.x;
                #pragma unroll
                for (int i = 0; i < 4; ++i) {
                    const int e = vei * 4 + i;
                    const u32 pk = (u32)bfb(pa_[i]) | ((u32)bfb(pb_[i]) << 16);
                    *(u32*)(void*)(&ldsVT[cur ^ 1][0] + ((e * 128 + vrp * 4) ^ swz8(e))) = pk;
                }
            }
            if (st + 2 < ntile) {
                const float* kp = kbase + (size_t)(st + 2) * TS * HE;
                const float* vp = vbase + (size_t)(st + 2) * TS * HE;
                ka = *(const float4*)(kp); kb2 = *(const float4*)(kp + 4);
                va = *(const float4*)(vp); vb2 = *(const float4*)(vp + HE);
            }
        }
        if (st <= ta) {   // wave-active tile
            f4v acc[4];
            #pragma unroll
            for (int cb = 0; cb < 4; ++cb) {
                const int sr = cb * 16 + le;
                bf8 k0 = *(const bf8*)(void*)(&ldsK[cur][0] + ((sr * 128 +  0 + g * 16) ^ swz8(sr)));
                bf8 k1 = *(const bf8*)(void*)(&ldsK[cur][0] + ((sr * 128 + 64 + g * 16) ^ swz8(sr)));
                f4v a = {0.f, 0.f, 0.f, 0.f};
                a = mfma16(qf0, k0, a);
                a = mfma16(qf1, k1, a);
                acc[cb] = a;
            }
            // p (overwrites acc) + P -> wave-private LDS (bf16)
            #pragma unroll
            for (int cb = 0; cb < 4; ++cb) {
                const float km = ldsKM[s0 + cb * 16 + le];
                const int s = s0 + cb * 16 + le;
                #pragma unroll
                for (int r = 0; r < 4; ++r) {
                    float z = acc[cb][r] * SCALEF + km;
                    if (s > lbase + r) z = NEGBIG;
                    const float p = __expf(z - C[r]);   // exact 0 for masked/causal/dead
                    acc[cb][r] = p;
                    const int row = g * 4 + r;          // wave-local row 0..15
                    *(u16*)(void*)(myP + ((row * 128 + (cb * 16 + le) * 2) ^ swz8(row))) = bfb(p);
                }
            }
            // PAIRED A stores: stash first tile of a pair; on the second (or
            // last) tile, write both tiles per row back-to-back -> 512B of
            // contiguous addresses in 8 consecutive store instructions.
            if (!havePend && st != ta) {
                #pragma unroll
                for (int cb = 0; cb < 4; ++cb)
                    #pragma unroll
                    for (int r = 0; r < 4; ++r) pend[cb][r] = acc[cb][r];
                pbase = s0;
                havePend = true;
            } else {
                #pragma unroll
                for (int r = 0; r < 4; ++r) {
                    if (!qm[r]) {
                        float* rp = outF + A_BASE
                            + (size_t)((size_t)bh * LL + l0 + w * 16 + g * 4 + r) * SS + le;
                        if (havePend) {
                            #pragma unroll
                            for (int cb = 0; cb < 4; ++cb)
                                rp[pbase + cb * 16] = pend[cb][r];
                        }
                        #pragma unroll
                        for (int cb = 0; cb < 4; ++cb)
                            rp[s0 + cb * 16] = acc[cb][r];
                    }
                }
                havePend = false;
            }
            asm volatile("s_waitcnt lgkmcnt(0)" ::: "memory");   // own P writes done

            #pragma unroll
            for (int kkb = 0; kkb < 2; ++kkb) {
                bf8 pa = *(const bf8*)(void*)(myP + ((le * 128 + kkb * 64 + g * 16) ^ swz8(le)));
                #pragma unroll
                for (int eb = 0; eb < 4; ++eb) {
                    const int e = eb * 16 + le;
                    bf8 vb = *(const bf8*)(void*)(&ldsVT[cur][0] + ((e * 128 + kkb * 64 + g * 16) ^ swz8(e)));
                    O[eb] = mfma16(pa, vb, O[eb]);
                }
            }
        }
        barrier_lds();   // dbuf[cur] reads done; dbuf[cur^1] writes visible
        cur ^= 1;
    }

    // V output (B,L,H,E) fp32 (exact 0 for masked rows since p==0 -> O==0)
    #pragma unroll
    for (int eb = 0; eb < 4; ++eb) {
        #pragma unroll
        for (int r = 0; r < 4; ++r) {
            const int l = lbase + r;
            outF[((size_t)(b * LL + l) * HH + h) * EE + eb * 16 + le] = O[eb][r];
        }
    }
}

extern "C" void kernel_launch(void* const* d_in, const int* in_sizes, int n_in,
                              void* d_out, int out_size, void* d_ws, size_t ws_size,
                              hipStream_t stream) {
    const float* Q = (const float*)d_in[0];   // fp32
    const float* K = (const float*)d_in[1];
    const float* V = (const float*)d_in[2];
    const void* mk = d_in[3];                 // mask_miss_k (B,S,1), nonzero = missing
    const void* mq = d_in[4];                 // mask_miss_q (B,L,1)
    // d_in[5] = pos (arange -> causal is s > l), d_in[6] = causal_mask (always 1)
    float* outF = (float*)d_out;              // fp32: V | A | entropy

    dim3 blk(512), grid(BB * HH * 16);        // 512 blocks -> 2 co-resident/CU
    hipLaunchKernelGGL(k_fused, grid, blk, 0, stream, Q, K, V, mk, mq, outF);
}

// Round 17
// 193.234 us; speedup vs baseline: 1.2541x; 1.2541x over previous
//
#include <hip/hip_runtime.h>

// Problem constants (fixed by the reference)
#define BB 2
#define LL 2048
#define SS 2048
#define HH 16
#define EE 64
#define HE (HH*EE)          // fp32 elements per token row: 1024
#define TS 64               // s-cols per tile
#define SCALEF 0.125f       // 1/sqrt(64)
#define NEGBIG (-1e30f)     // -inf stand-in; exp underflows to exact 0

typedef __bf16 bf8 __attribute__((ext_vector_type(8)));
typedef float f4v __attribute__((ext_vector_type(4)));
typedef unsigned int u32;
typedef unsigned short u16;

// d_out layout (fp32 elements): V | A | entropy, concatenated in return order
#define V_ELEMS  ((size_t)BB*LL*HH*EE)              // 4,194,304
#define A_BASE   (V_ELEMS)
#define ENT_BASE (A_BASE + (size_t)BB*HH*LL*SS)     // + 134,217,728

__device__ __forceinline__ u16 bfb(float f) {  // fp32 -> bf16 RNE
    u32 u = __builtin_bit_cast(u32, f);
    return (u16)((u + 0x7fffu + ((u >> 16) & 1u)) >> 16);
}
// XOR swizzle on byte-addr bits 4-6 (LDS bank spread for 128B-row tiles)
__device__ __forceinline__ int swz8(int r) { return (((r) & 7) ^ (((r) >> 3) & 7)) << 4; }

__device__ __forceinline__ f4v mfma16(bf8 a, bf8 b, f4v c) {
    return __builtin_amdgcn_mfma_f32_16x16x32_bf16(a, b, c, 0, 0, 0);
}
// Masks may arrive as 1-byte bool or 4-byte int32 — runtime-detected.
__device__ __forceinline__ int maskv(const void* p, int i, int isB) {
    return isB ? (int)((const unsigned char*)p)[i] : ((const int*)p)[i];
}
// LDS-only barrier: waits ds ops, does NOT drain vmcnt — global loads/stores
// stay in flight across it (T14).
__device__ __forceinline__ void barrier_lds() {
    asm volatile("s_waitcnt lgkmcnt(0)" ::: "memory");
    __builtin_amdgcn_s_barrier();
    asm volatile("" ::: "memory");
}
__device__ __forceinline__ uint4 pack8(float4 f0, float4 f1) {  // 8 fp32 -> 8 bf16
    uint4 wv;
    wv.x = bfb(f0.x) | ((u32)bfb(f0.y) << 16);
    wv.y = bfb(f0.z) | ((u32)bfb(f0.w) << 16);
    wv.z = bfb(f1.x) | ((u32)bfb(f1.y) << 16);
    wv.w = bfb(f1.z) | ((u32)bfb(f1.w) << 16);
    return wv;
}

// Stage a 128x64 fp32 tile (row stride HE) into LDS as bf16 [128][64] swizzled. 512 thr.
__device__ __forceinline__ void stage128x64(const float* __restrict__ src,
                                            char* lds, int tid) {
    const int r = tid >> 2, seg = tid & 3;
    const float* rp = src + (size_t)r * HE + seg * 16;
    float4 f0 = *(const float4*)(rp + 0);
    float4 f1 = *(const float4*)(rp + 4);
    float4 f2 = *(const float4*)(rp + 8);
    float4 f3 = *(const float4*)(rp + 12);
    const int base = r * 128 + seg * 32;
    *(uint4*)(void*)(lds + ((base +  0) ^ swz8(r))) = pack8(f0, f1);
    *(uint4*)(void*)(lds + ((base + 16) ^ swz8(r))) = pack8(f2, f3);
}

// One block = (b, h, ONE 128-row band); 512 blocks x 512 thr -> 2 blocks/CU.
// R15 structure (best: 195us) with ONE change: band schedule pairs heavy and
// light bands across the two dispatch waves -- slot s<8 carries band 15-s
// (first resident block), slot s>=8 carries band s-8 (second resident block),
// so under round-robin dispatch every CU's two blocks sum to exactly 34
// causal tiles (was 20..48, a 2.4x tail).
__global__ __launch_bounds__(512, 4) void k_fused(
    const float* __restrict__ Qg, const float* __restrict__ Kg, const float* __restrict__ Vg,
    const void* __restrict__ mk, const void* __restrict__ mq,
    float* __restrict__ outF)
{
    __shared__ __align__(16) char ldsP[16384];      // Q stage / 8 wave-private 2KB P regions
    __shared__ __align__(16) char ldsK[2][8192];    // K dbuf [64 s][64 e] bf16
    __shared__ __align__(16) char ldsVT[2][8192];   // V^T dbuf [64 e][64 s] bf16
    __shared__ float ldsKM[SS];                     // k-mask bias row (8KB)
    __shared__ int sFlag;

    // Decode: XCD-major; balanced band pairing across the two dispatch waves.
    const int blk = blockIdx.x;
    const int xcd = blk & 7, idx = blk >> 3;        // idx 0..63
    const int bh  = xcd * 4 + (idx & 3);            // 0..31
    const int slot = idx >> 2;                      // 0..15
    const int band = (slot < 8) ? (15 - slot) : (slot - 8);  // pairs sum to 15
    const int b = bh >> 4, h = bh & 15;
    const int tid = threadIdx.x;
    const int w = tid >> 6, lane = tid & 63, g = lane >> 4, le = lane & 15;

    int isB;   // mask element-width detection (1B bool vs 4B int32)
    {
        const unsigned char* c = (const unsigned char*)mk;
        unsigned acc = 0;
        #pragma unroll
        for (int j = 0; j < 8; ++j) {
            const int off = tid + j * 512;
            if (off & 3) acc |= c[off];
        }
        if (tid == 0) sFlag = 0;
        __syncthreads();
        if (acc) atomicOr(&sFlag, 1);
        __syncthreads();
        isB = sFlag;
    }
    for (int i = tid; i < SS; i += 512)
        ldsKM[i] = maskv(mk, b * SS + i, isB) ? NEGBIG : 0.f;

    const float* Qb = Qg + (size_t)b * LL * HE + h * EE;
    const float* Kb = Kg + (size_t)b * SS * HE + h * EE;
    const float* Vb = Vg + (size_t)b * SS * HE + h * EE;

    const int l0 = band * 128;
    const int lbase = l0 + w * 16 + g * 4;   // this lane's 4 C-layout rows
    const int whi = l0 + w * 16 + 15;        // wave's highest row
    const int ta  = whi >> 6;                // wave's last causal 64-col tile
    const int ntile = 2 * (band + 1);        // block-level causal tiles

    // ---- stage Q tile [128][64] -> ldsP, grab fragments ----
    stage128x64(Qb + (size_t)l0 * HE, ldsP, tid);
    __syncthreads();
    const int qr = w * 16 + le;
    bf8 qf0 = *(const bf8*)(void*)(ldsP + ((qr * 128 +  0 + g * 16) ^ swz8(qr)));
    bf8 qf1 = *(const bf8*)(void*)(ldsP + ((qr * 128 + 64 + g * 16) ^ swz8(qr)));
    barrier_lds();   // ldsP free for P after this

    // per-thread staging geometry
    const int kr = tid >> 3, ksg = tid & 7;         // K: 64 rows x 8 segs of 8
    const float* kbase = Kb + (size_t)kr * HE + ksg * 8;
    const int koff = (kr * 128 + ksg * 16) ^ swz8(kr);
    const int vrp = tid >> 4, vei = tid & 15;       // V^T: 32 row-pairs x 16 e-quads
    const float* vbase = Vb + (size_t)(2 * vrp) * HE + vei * 4;

    // ================= PASS 1: per-row M, D, T (1 barrier/tile) =================
    float M[4], D[4], T[4];
    #pragma unroll
    for (int r = 0; r < 4; ++r) { M[r] = NEGBIG; D[r] = 0.f; T[r] = 0.f; }

    float4 ka = *(const float4*)(kbase);
    float4 kb2 = *(const float4*)(kbase + 4);
    *(uint4*)(void*)(&ldsK[0][0] + koff) = pack8(ka, kb2);
    if (ntile > 1) {
        const float* kp = kbase + (size_t)TS * HE;
        ka = *(const float4*)(kp); kb2 = *(const float4*)(kp + 4);
    }
    barrier_lds();
    int cur = 0;

    for (int st = 0; st < ntile; ++st) {
        const int s0 = st * TS;
        if (st + 1 < ntile) {   // stage next tile from regs, issue st+2 loads
            *(uint4*)(void*)(&ldsK[cur ^ 1][0] + koff) = pack8(ka, kb2);
            if (st + 2 < ntile) {
                const float* kp = kbase + (size_t)(st + 2) * TS * HE;
                ka = *(const float4*)(kp); kb2 = *(const float4*)(kp + 4);
            }
        }
        if (s0 <= whi) {   // causal skip
            f4v acc[4];
            float tm[4] = {NEGBIG, NEGBIG, NEGBIG, NEGBIG};
            #pragma unroll
            for (int cb = 0; cb < 4; ++cb) {
                const int sr = cb * 16 + le;
                bf8 k0 = *(const bf8*)(void*)(&ldsK[cur][0] + ((sr * 128 +  0 + g * 16) ^ swz8(sr)));
                bf8 k1 = *(const bf8*)(void*)(&ldsK[cur][0] + ((sr * 128 + 64 + g * 16) ^ swz8(sr)));
                f4v a = {0.f, 0.f, 0.f, 0.f};
                a = mfma16(qf0, k0, a);
                a = mfma16(qf1, k1, a);
                const float km = ldsKM[s0 + cb * 16 + le];
                const int s = s0 + cb * 16 + le;
                #pragma unroll
                for (int r = 0; r < 4; ++r) {
                    float z = a[r] * SCALEF + km;       // scale*(score + m_k)
                    if (s > lbase + r) z = NEGBIG;      // causal (pos == arange)
                    acc[cb][r] = z;
                    tm[r] = fmaxf(tm[r], z);
                }
            }
            // tile-level rescale: one shared max per row-tile, 1 exp per element
            #pragma unroll
            for (int r = 0; r < 4; ++r) {
                #pragma unroll
                for (int msk = 1; msk < 16; msk <<= 1)
                    tm[r] = fmaxf(tm[r], __shfl_xor(tm[r], msk));
                const float mn  = fmaxf(M[r], tm[r]);
                const float fre = __expf(M[r] - mn);    // 0 when jumping off -1e30
                float ed = 0.f, et = 0.f;
                #pragma unroll
                for (int cb = 0; cb < 4; ++cb) {
                    const float z = acc[cb][r];
                    const float e = __expf(z - mn);
                    ed += e; et += e * z;
                }
                D[r] = D[r] * fre + ed;
                T[r] = T[r] * fre + et;
                M[r] = mn;
            }
        }
        barrier_lds();
        cur ^= 1;
    }

    // butterfly-merge over the 16-lane group; C = logsumexp, entropy out
    float C[4];
    bool qm[4];   // q-masked flag for this lane's rows
    #pragma unroll
    for (int r = 0; r < 4; ++r) {
        #pragma unroll
        for (int msk = 1; msk < 16; msk <<= 1) {
            const float Mo = __shfl_xor(M[r], msk);
            const float Do = __shfl_xor(D[r], msk);
            const float To = __shfl_xor(T[r], msk);
            const float mn = fmaxf(M[r], Mo);
            const float fa = __expf(M[r] - mn);
            const float fb = __expf(Mo  - mn);
            D[r] = D[r] * fa + Do * fb;
            T[r] = T[r] * fa + To * fb;
            M[r] = mn;
        }
        const int l = lbase + r;
        qm[r] = maskv(mq, b * LL + l, isB) != 0;
        const bool valid = (M[r] > -1e29f) && !qm[r];
        C[r] = valid ? (M[r] + __logf(D[r])) : 1e30f;     // p = exp(z - C); dead rows -> 0
        const float ent = valid ? (C[r] - T[r] / D[r]) : 0.f;
        if (le == 0) outF[ENT_BASE + (size_t)bh * LL + l] = ent;
    }

    float* const Arow0 = outF + A_BASE + ((size_t)bh * LL + l0) * SS;

    // ---- q-masked rows: ENTIRE A row is exactly 0 -> full-row sequential fill
    //      (1KB per instruction, DRAM-page friendly). Wave-uniform branch. ----
    {
        const f4v zz = {0.f, 0.f, 0.f, 0.f};
        for (int k = 0; k < 16; ++k) {
            const int row = w * 16 + k;
            if (maskv(mq, b * LL + l0 + row, isB)) {
                float* dst = Arow0 + (size_t)row * SS + lane * 4;
                #pragma unroll
                for (int j = 0; j < 8; ++j)
                    *(f4v*)(void*)(dst + j * 256) = zz;
            }
        }
    }

    // ---- causal zero-tail for NON-masked rows (masked rows fully filled) ----
    {
        const int rr = lane >> 2, cc = lane & 3;
        const int row = w * 16 + rr;
        if (!maskv(mq, b * LL + l0 + row, isB)) {
            float* dst0 = Arow0 + (size_t)row * SS;
            const f4v zz = {0.f, 0.f, 0.f, 0.f};
            for (int c = (ta + 1) * TS + cc * 4; c < SS; c += 16)
                *(f4v*)(void*)(dst0 + c) = zz;
        }
    }

    // ================= PASS 2: A (fp32) + O = A·V (1 barrier/tile) =================
    f4v O[4];
    #pragma unroll
    for (int eb = 0; eb < 4; ++eb) O[eb] = (f4v){0.f, 0.f, 0.f, 0.f};

    ka  = *(const float4*)(kbase);
    kb2 = *(const float4*)(kbase + 4);
    float4 va  = *(const float4*)(vbase);
    float4 vb2 = *(const float4*)(vbase + HE);
    *(uint4*)(void*)(&ldsK[0][0] + koff) = pack8(ka, kb2);
    {
        const float* pa_ = &va.x; const float* pb_ = &vb2.x;
        #pragma unroll
        for (int i = 0; i < 4; ++i) {
            const int e = vei * 4 + i;
            const u32 pk = (u32)bfb(pa_[i]) | ((u32)bfb(pb_[i]) << 16);
            *(u32*)(void*)(&ldsVT[0][0] + ((e * 128 + vrp * 4) ^ swz8(e))) = pk;
        }
    }
    if (ntile > 1) {
        const float* kp = kbase + (size_t)TS * HE;
        const float* vp = vbase + (size_t)TS * HE;
        ka = *(const float4*)(kp); kb2 = *(const float4*)(kp + 4);
        va = *(const float4*)(vp); vb2 = *(const float4*)(vp + HE);
    }
    barrier_lds();
    cur = 0;
    char* const myP = ldsP + w * 2048;

    for (int st = 0; st < ntile; ++st) {
        const int s0 = st * TS;
        if (st + 1 < ntile) {   // stage next tiles from regs, prefetch st+2
            *(uint4*)(void*)(&ldsK[cur ^ 1][0] + koff) = pack8(ka, kb2);
            {
                const float* pa_ = &va.x; const float* pb_ = &vb2.x;
                #pragma unroll
                for (int i = 0; i < 4; ++i) {
                    const int e = vei * 4 + i;
                    const u32 pk = (u32)bfb(pa_[i]) | ((u32)bfb(pb_[i]) << 16);
                    *(u32*)(void*)(&ldsVT[cur ^ 1][0] + ((e * 128 + vrp * 4) ^ swz8(e))) = pk;
                }
            }
            if (st + 2 < ntile) {
                const float* kp = kbase + (size_t)(st + 2) * TS * HE;
                const float* vp = vbase + (size_t)(st + 2) * TS * HE;
                ka = *(const float4*)(kp); kb2 = *(const float4*)(kp + 4);
                va = *(const float4*)(vp); vb2 = *(const float4*)(vp + HE);
            }
        }
        if (st <= ta) {   // wave-active tile
            f4v acc[4];
            #pragma unroll
            for (int cb = 0; cb < 4; ++cb) {
                const int sr = cb * 16 + le;
                bf8 k0 = *(const bf8*)(void*)(&ldsK[cur][0] + ((sr * 128 +  0 + g * 16) ^ swz8(sr)));
                bf8 k1 = *(const bf8*)(void*)(&ldsK[cur][0] + ((sr * 128 + 64 + g * 16) ^ swz8(sr)));
                f4v a = {0.f, 0.f, 0.f, 0.f};
                a = mfma16(qf0, k0, a);
                a = mfma16(qf1, k1, a);
                acc[cb] = a;
            }
            // P -> wave-private LDS (bf16); A scattered stores ONLY for live rows
            #pragma unroll
            for (int cb = 0; cb < 4; ++cb) {
                const float km = ldsKM[s0 + cb * 16 + le];
                const int s = s0 + cb * 16 + le;
                #pragma unroll
                for (int r = 0; r < 4; ++r) {
                    float z = acc[cb][r] * SCALEF + km;
                    if (s > lbase + r) z = NEGBIG;
                    const float p = __expf(z - C[r]);   // exact 0 for masked/causal/dead
                    const int row = g * 4 + r;          // wave-local row 0..15
                    *(u16*)(void*)(myP + ((row * 128 + (cb * 16 + le) * 2) ^ swz8(row))) = bfb(p);
                    if (!qm[r])
                        outF[A_BASE + ((size_t)bh * LL + (l0 + w * 16 + row)) * SS + s] = p;
                }
            }
            asm volatile("s_waitcnt lgkmcnt(0)" ::: "memory");   // own P writes done

            #pragma unroll
            for (int kkb = 0; kkb < 2; ++kkb) {
                bf8 pa = *(const bf8*)(void*)(myP + ((le * 128 + kkb * 64 + g * 16) ^ swz8(le)));
                #pragma unroll
                for (int eb = 0; eb < 4; ++eb) {
                    const int e = eb * 16 + le;
                    bf8 vb = *(const bf8*)(void*)(&ldsVT[cur][0] + ((e * 128 + kkb * 64 + g * 16) ^ swz8(e)));
                    O[eb] = mfma16(pa, vb, O[eb]);
                }
            }
        }
        barrier_lds();   // dbuf[cur] reads done; dbuf[cur^1] writes visible
        cur ^= 1;
    }

    // V output (B,L,H,E) fp32 (exact 0 for masked rows since p==0 -> O==0)
    #pragma unroll
    for (int eb = 0; eb < 4; ++eb) {
        #pragma unroll
        for (int r = 0; r < 4; ++r) {
            const int l = lbase + r;
            outF[((size_t)(b * LL + l) * HH + h) * EE + eb * 16 + le] = O[eb][r];
        }
    }
}

extern "C" void kernel_launch(void* const* d_in, const int* in_sizes, int n_in,
                              void* d_out, int out_size, void* d_ws, size_t ws_size,
                              hipStream_t stream) {
    const float* Q = (const float*)d_in[0];   // fp32
    const float* K = (const float*)d_in[1];
    const float* V = (const float*)d_in[2];
    const void* mk = d_in[3];                 // mask_miss_k (B,S,1), nonzero = missing
    const void* mq = d_in[4];                 // mask_miss_q (B,L,1)
    // d_in[5] = pos (arange -> causal is s > l), d_in[6] = causal_mask (always 1)
    float* outF = (float*)d_out;              // fp32: V | A | entropy

    dim3 blk(512), grid(BB * HH * 16);        // 512 blocks -> 2 co-resident/CU
    hipLaunchKernelGGL(k_fused, grid, blk, 0, stream, Q, K, V, mk, mq, outF);
}